// Round 6
// baseline (238.858 us; speedup 1.0000x reference)
//
#include <hip/hip_runtime.h>

// Problem constants (from reference): B=8, C=3, H=512, W=512
constexpr int Cc = 3;
constexpr int Hc = 512;
constexpr int Wc = 512;
constexpr int HW = 262144;             // 512*512 = 2^18
constexpr int NPIX = 8 * HW;           // 2097152
constexpr int NGRP = NPIX / 4;         // 524288 groups of 4 consecutive pixels
constexpr int GPB  = 512;              // groups per block (2 per thread)
constexpr int NBLK = NGRP / GPB;       // 1024 blocks

// ws layout: [0, NBLK) doubles = per-block partial sums, then NBLK floats = maxes

typedef float fx4 __attribute__((ext_vector_type(4)));

__device__ __forceinline__ fx4 ntload4(const float* p) {
    return __builtin_nontemporal_load((const fx4*)p);
}

struct Grp {
    fx4 d0, d1, d2;           // residuals (4 pixels x 3 channels)
    fx4 sv[9];                // sigma (4 pixels x 9 floats)
};

__device__ __forceinline__ void load_group(
    const float* __restrict__ target, const float* __restrict__ mu,
    const float* __restrict__ sigma_y, int g, Grp& G)
{
    int p0 = g << 2;                 // first pixel (multiple of 4)
    int b  = p0 >> 18;               // / HW
    int hw = p0 & (HW - 1);          // % HW (multiple of 4)
    long long base = (long long)b * (Cc * HW) + hw;

    fx4 t0 = ntload4(target + base);
    fx4 t1 = ntload4(target + base + HW);
    fx4 t2 = ntload4(target + base + 2 * HW);
    fx4 m0 = ntload4(mu + base);
    fx4 m1 = ntload4(mu + base + HW);
    fx4 m2 = ntload4(mu + base + 2 * HW);

    const float* s = sigma_y + (long long)p0 * 9;
    #pragma unroll
    for (int i = 0; i < 9; ++i) G.sv[i] = ntload4(s + 4 * i);

    G.d0 = t0 - m0;
    G.d1 = t1 - m1;
    G.d2 = t2 - m2;
}

__device__ __forceinline__ void compute_group(const Grp& G, double& local_sum, float& local_max)
{
    const float* sf = (const float*)G.sv;
    const float T0[4] = {G.d0.x, G.d0.y, G.d0.z, G.d0.w};
    const float T1[4] = {G.d1.x, G.d1.y, G.d1.z, G.d1.w};
    const float T2[4] = {G.d2.x, G.d2.y, G.d2.z, G.d2.w};

    #pragma unroll
    for (int i = 0; i < 4; ++i) {
        const float* s = sf + i * 9;
        float s00 = s[0], s01 = s[1], s02 = s[2];
        float s11 = s[4], s12 = s[5], s22 = s[8];

        float a00 = s11 * s22 - s12 * s12;
        float a01 = s02 * s12 - s01 * s22;
        float a02 = s01 * s12 - s02 * s11;
        float a11 = s00 * s22 - s02 * s02;
        float a12 = s01 * s02 - s00 * s12;
        float a22 = s00 * s11 - s01 * s01;

        float det = s00 * a00 + s01 * a01 + s02 * a02;

        float t0 = T0[i], t1 = T1[i], t2 = T2[i];
        float quad = t0 * t0 * a00 + t1 * t1 * a11 + t2 * t2 * a22
                   + 2.0f * (t0 * t1 * a01 + t0 * t2 * a02 + t1 * t2 * a12);

        float t1term = 0.5f * quad / det;
        float t2term = 0.5f * logf(det);

        local_sum += (double)(t1term + t2term);
        local_max = fmaxf(local_max, t1term);
    }
}

__global__ __launch_bounds__(256) void map_loss_main(
    const float* __restrict__ target,
    const float* __restrict__ mu,
    const float* __restrict__ sigma_y,
    double* __restrict__ part_sum,
    float* __restrict__ part_max)
{
    double local_sum = 0.0;
    float local_max = 0.0f;

    // two groups per thread; both loaded fully (30 independent float4 nt loads
    // in flight) before any compute
    int g0 = blockIdx.x * GPB + threadIdx.x;
    int g1 = g0 + 256;

    Grp A, B;
    load_group(target, mu, sigma_y, g0, A);
    load_group(target, mu, sigma_y, g1, B);

    compute_group(A, local_sum, local_max);
    compute_group(B, local_sum, local_max);

    // wave (64-lane) reduction
    for (int off = 32; off > 0; off >>= 1) {
        local_sum += __shfl_down(local_sum, off, 64);
        local_max = fmaxf(local_max, __shfl_down(local_max, off, 64));
    }

    __shared__ double ssum[4];
    __shared__ float  smax[4];
    int wave = threadIdx.x >> 6;
    int lane = threadIdx.x & 63;
    if (lane == 0) { ssum[wave] = local_sum; smax[wave] = local_max; }
    __syncthreads();

    if (threadIdx.x == 0) {
        part_sum[blockIdx.x] = ssum[0] + ssum[1] + ssum[2] + ssum[3];
        part_max[blockIdx.x] = fmaxf(fmaxf(smax[0], smax[1]), fmaxf(smax[2], smax[3]));
    }
}

__global__ __launch_bounds__(256) void map_loss_finalize(
    const double* __restrict__ part_sum,
    const float* __restrict__ part_max,
    float* __restrict__ out)
{
    double s = 0.0;
    float m = 0.0f;
    for (int i = threadIdx.x; i < NBLK; i += 256) {
        s += part_sum[i];
        m = fmaxf(m, part_max[i]);
    }

    for (int off = 32; off > 0; off >>= 1) {
        s += __shfl_down(s, off, 64);
        m = fmaxf(m, __shfl_down(m, off, 64));
    }

    __shared__ double ssum[4];
    __shared__ float  smax[4];
    int wave = threadIdx.x >> 6;
    int lane = threadIdx.x & 63;
    if (lane == 0) { ssum[wave] = s; smax[wave] = m; }
    __syncthreads();

    if (threadIdx.x == 0) {
        double bs = ssum[0] + ssum[1] + ssum[2] + ssum[3];
        float  bm = fmaxf(fmaxf(smax[0], smax[1]), fmaxf(smax[2], smax[3]));
        out[0] = (bm > 1e8f) ? 0.0f : (float)(bs / (double)NPIX);
    }
}

extern "C" void kernel_launch(void* const* d_in, const int* in_sizes, int n_in,
                              void* d_out, int out_size, void* d_ws, size_t ws_size,
                              hipStream_t stream) {
    const float* target  = (const float*)d_in[0];
    const float* mu      = (const float*)d_in[1];
    // d_in[2] = sigma_mu (unused), d_in[3] = sigma_n (unused)
    const float* sigma_y = (const float*)d_in[4];
    float* out = (float*)d_out;

    double* part_sum = (double*)d_ws;
    float*  part_max = (float*)((char*)d_ws + NBLK * sizeof(double));
    // every slot is written unconditionally by its block — no pre-zeroing needed

    map_loss_main<<<NBLK, 256, 0, stream>>>(target, mu, sigma_y, part_sum, part_max);
    map_loss_finalize<<<1, 256, 0, stream>>>(part_sum, part_max, out);
}

// Round 7
// 218.306 us; speedup vs baseline: 1.0941x; 1.0941x over previous
//
#include <hip/hip_runtime.h>

// Problem constants (from reference): B=8, C=3, H=512, W=512
constexpr int Cc = 3;
constexpr int HW = 262144;             // 512*512 = 2^18
constexpr int NPIX = 8 * HW;           // 2097152

constexpr int TILE = 512;              // pixels per block (2 per thread)
constexpr int NBLK = NPIX / TILE;      // 4096 blocks
constexpr int TF4  = TILE * 9 / 4;     // 1152 float4 of sigma per tile (18 KB)

// ws layout: [0, NBLK) doubles = per-block partial sums, then NBLK floats = maxes

__global__ __launch_bounds__(256) void map_loss_main(
    const float* __restrict__ target,
    const float* __restrict__ mu,
    const float* __restrict__ sigma_y,
    double* __restrict__ part_sum,
    float* __restrict__ part_max)
{
    __shared__ float4 smem[TF4];       // 18432 B

    const int t = threadIdx.x;

    // ---- stage sigma tile: pure block-coalesced float4 stream ----
    const float4* s4 = (const float4*)sigma_y + (long long)blockIdx.x * TF4;
    #pragma unroll
    for (int j = 0; j < 4; ++j)
        smem[j * 256 + t] = s4[j * 256 + t];
    if (t < TF4 - 1024)                 // 128 threads = waves 0,1 -> wave-uniform
        smem[1024 + t] = s4[1024 + t];
    __syncthreads();

    // ---- per-thread: 2 consecutive pixels ----
    const int p0 = blockIdx.x * TILE + 2 * t;
    const int b  = p0 >> 18;            // / HW
    const int hw = p0 & (HW - 1);       // % HW (even)
    const long long base = (long long)b * (Cc * HW) + hw;

    // target/mu: 3 channels as coalesced float2 (8 B lane stride)
    const float2* tg = (const float2*)(target + base);
    const float2* mm = (const float2*)(mu + base);
    float2 d0 = tg[0];        float2 m0 = mm[0];
    float2 d1 = tg[HW / 2];   float2 m1 = mm[HW / 2];
    float2 d2 = tg[HW];       float2 m2 = mm[HW];
    const float T0[2] = {d0.x - m0.x, d0.y - m0.y};
    const float T1[2] = {d1.x - m1.x, d1.y - m1.y};
    const float T2[2] = {d2.x - m2.x, d2.y - m2.y};

    // sigma for my 2 pixels: 18 consecutive floats from LDS
    // (lane stride 18 floats -> 2-way bank aliasing = free, m136)
    const float* sp = (const float*)smem + (size_t)t * 18;
    float S[18];
    #pragma unroll
    for (int k = 0; k < 18; ++k) S[k] = sp[k];

    double local_sum = 0.0;
    float  local_max = 0.0f;

    #pragma unroll
    for (int i = 0; i < 2; ++i) {
        const float* s = S + i * 9;
        float s00 = s[0], s01 = s[1], s02 = s[2];
        float s11 = s[4], s12 = s[5], s22 = s[8];

        // adjugate (symmetric)
        float a00 = s11 * s22 - s12 * s12;
        float a01 = s02 * s12 - s01 * s22;
        float a02 = s01 * s12 - s02 * s11;
        float a11 = s00 * s22 - s02 * s02;
        float a12 = s01 * s02 - s00 * s12;
        float a22 = s00 * s11 - s01 * s01;

        float det = s00 * a00 + s01 * a01 + s02 * a02;

        float t0 = T0[i], t1 = T1[i], t2 = T2[i];
        float quad = t0 * t0 * a00 + t1 * t1 * a11 + t2 * t2 * a22
                   + 2.0f * (t0 * t1 * a01 + t0 * t2 * a02 + t1 * t2 * a12);

        float t1term = 0.5f * quad / det;
        float t2term = 0.5f * logf(det);

        local_sum += (double)(t1term + t2term);
        local_max = fmaxf(local_max, t1term);
    }

    // ---- wave (64-lane) reduction ----
    for (int off = 32; off > 0; off >>= 1) {
        local_sum += __shfl_down(local_sum, off, 64);
        local_max = fmaxf(local_max, __shfl_down(local_max, off, 64));
    }

    __shared__ double ssum[4];
    __shared__ float  smax[4];
    int wave = t >> 6;
    int lane = t & 63;
    if (lane == 0) { ssum[wave] = local_sum; smax[wave] = local_max; }
    __syncthreads();

    if (t == 0) {
        // per-block partials to DISTINCT addresses — no atomics, no contention
        part_sum[blockIdx.x] = ssum[0] + ssum[1] + ssum[2] + ssum[3];
        part_max[blockIdx.x] = fmaxf(fmaxf(smax[0], smax[1]), fmaxf(smax[2], smax[3]));
    }
}

__global__ __launch_bounds__(256) void map_loss_finalize(
    const double* __restrict__ part_sum,
    const float* __restrict__ part_max,
    float* __restrict__ out)
{
    double s = 0.0;
    float m = 0.0f;
    for (int i = threadIdx.x; i < NBLK; i += 256) {
        s += part_sum[i];
        m = fmaxf(m, part_max[i]);
    }

    for (int off = 32; off > 0; off >>= 1) {
        s += __shfl_down(s, off, 64);
        m = fmaxf(m, __shfl_down(m, off, 64));
    }

    __shared__ double ssum[4];
    __shared__ float  smax[4];
    int wave = threadIdx.x >> 6;
    int lane = threadIdx.x & 63;
    if (lane == 0) { ssum[wave] = s; smax[wave] = m; }
    __syncthreads();

    if (threadIdx.x == 0) {
        double bs = ssum[0] + ssum[1] + ssum[2] + ssum[3];
        float  bm = fmaxf(fmaxf(smax[0], smax[1]), fmaxf(smax[2], smax[3]));
        out[0] = (bm > 1e8f) ? 0.0f : (float)(bs / (double)NPIX);
    }
}

extern "C" void kernel_launch(void* const* d_in, const int* in_sizes, int n_in,
                              void* d_out, int out_size, void* d_ws, size_t ws_size,
                              hipStream_t stream) {
    const float* target  = (const float*)d_in[0];
    const float* mu      = (const float*)d_in[1];
    // d_in[2] = sigma_mu (unused), d_in[3] = sigma_n (unused)
    const float* sigma_y = (const float*)d_in[4];
    float* out = (float*)d_out;

    double* part_sum = (double*)d_ws;
    float*  part_max = (float*)((char*)d_ws + NBLK * sizeof(double));
    // every slot is written unconditionally by its block — no pre-zeroing needed

    map_loss_main<<<NBLK, 256, 0, stream>>>(target, mu, sigma_y, part_sum, part_max);
    map_loss_finalize<<<1, 256, 0, stream>>>(part_sum, part_max, out);
}